// Round 21
// baseline (656.834 us; speedup 1.0000x reference)
//
#include <hip/hip_runtime.h>
#include <hip/hip_bf16.h>
#include <math.h>
#include <float.h>

#define NC 256
#define NT 2048

typedef __attribute__((ext_vector_type(4))) float f32x4;
typedef __attribute__((ext_vector_type(8))) short short8;
typedef __attribute__((ext_vector_type(4))) short short4v;
typedef __attribute__((ext_vector_type(4))) unsigned short ushort4v;

// ws layout (34,340,864 B total — known-good size):
//   sq   double[8*2048]        @ 0
//   A-region @ A_OFF: phase A = Xhl u32[8][256][2048]; phase B = A float
//   E-region @ E_OFF: phase A = xT float[8*2048*256]; phase B = E float
//   nb   int[8*2048*10]        @ NB_OFF
// d_out scratch until k_epi: wsc u16 @ 0; cand u16 @ u16-elem 1<<20; cand2 u16 @ (1<<20)+(1<<19)
#define SQ_OFF 0
#define A_OFF  131072
#define E_OFF  16908288
#define NB_OFF 33685504

__device__ __forceinline__ int load_nf(const int* __restrict__ nf, int b) {
    bool is64 = (nf[1] == 0) & (nf[3] == 0) & (nf[5] == 0) & (nf[7] == 0);
    return is64 ? nf[2 * b] : nf[b];
}

__device__ __forceinline__ void split_bf16(float f, unsigned short& h, unsigned short& l) {
    __hip_bfloat16 hb = __float2bfloat16(f);
    float fh = __bfloat162float(hb);
    __hip_bfloat16 lb = __float2bfloat16(f - fh);
    h = *(unsigned short*)&hb;
    l = *(unsigned short*)&lb;
}

__device__ __forceinline__ short8 ld8(const unsigned short* p) {
    short4v a = *(const short4v*)p;
    short4v b = *(const short4v*)(p + 4);
    return __builtin_shufflevector(a, b, 0, 1, 2, 3, 4, 5, 6, 7);
}

__device__ __forceinline__ void store_hl(unsigned short* dh, unsigned short* dl,
                                         const unsigned int* pf) {
    ushort4v h0 = {(unsigned short)pf[0], (unsigned short)pf[1],
                   (unsigned short)pf[2], (unsigned short)pf[3]};
    ushort4v h1 = {(unsigned short)pf[4], (unsigned short)pf[5],
                   (unsigned short)pf[6], (unsigned short)pf[7]};
    ushort4v l0 = {(unsigned short)(pf[0] >> 16), (unsigned short)(pf[1] >> 16),
                   (unsigned short)(pf[2] >> 16), (unsigned short)(pf[3] >> 16)};
    ushort4v l1 = {(unsigned short)(pf[4] >> 16), (unsigned short)(pf[5] >> 16),
                   (unsigned short)(pf[6] >> 16), (unsigned short)(pf[7] >> 16)};
    *(ushort4v*)dh = h0;
    *(ushort4v*)(dh + 4) = h1;
    *(ushort4v*)dl = l0;
    *(ushort4v*)(dl + 4) = l1;
}

// ---------------- kernel 1: sq + packed bf16-split plane Xhl ----------------
__global__ __launch_bounds__(256) void k_sq(const float* __restrict__ x, double* __restrict__ sq,
                                            unsigned int* __restrict__ Xhl) {
    __shared__ double part[8][33];
    int b = blockIdx.y;
    int q0 = blockIdx.x * 32;
    int tid = threadIdx.x;
    int tt = tid & 31, cg = tid >> 5;
    const float* xp = x + (size_t)b * NC * NT + q0 + tt;
    unsigned int* xo = Xhl + (size_t)b * NC * NT + q0 + tt;
    double a = 0.0;
    #pragma unroll 8
    for (int i = 0; i < 32; ++i) {
        float f = xp[(size_t)(cg * 32 + i) * NT];
        double v = (double)f;
        a = fma(v, v, a);
        unsigned short h, l;
        split_bf16(f, h, l);
        xo[(size_t)(cg * 32 + i) * NT] = (unsigned int)h | ((unsigned int)l << 16);
    }
    part[cg][tt] = a;
    __syncthreads();
    if (tid < 32) {
        double s = part[0][tid];
        #pragma unroll
        for (int g = 1; g < 8; ++g) s += part[g][tid];
        sq[b * NT + q0 + tid] = s;
    }
}

// ---------------- kernel 1b: xT[b][t][c] = x[b][c][t] ----------------
__global__ __launch_bounds__(256) void k_xt(const float* __restrict__ x, float* __restrict__ xT) {
    __shared__ float T[64][65];
    int t0 = blockIdx.x * 64, c0 = blockIdx.y * 64, b = blockIdx.z;
    int tid = threadIdx.x;
    int j = tid & 63, i0 = tid >> 6;
    #pragma unroll
    for (int i = 0; i < 16; ++i) {
        int c = i * 4 + i0;
        T[c][j] = x[((size_t)b * NC + c0 + c) * NT + t0 + j];
    }
    __syncthreads();
    #pragma unroll
    for (int i = 0; i < 16; ++i) {
        int t = i * 4 + i0;
        xT[((size_t)b * NT + t0 + t) * NC + c0 + j] = T[j][t];
    }
}

// ---------------- kernel 1c: pre-split weights into d_out scratch ----------------
__global__ __launch_bounds__(256) void k_wsplit(const float* __restrict__ Wc, const float* __restrict__ Wm,
                                                unsigned short* __restrict__ wsc) {
    int o = blockIdx.x;
    int tid = threadIdx.x;
    #pragma unroll
    for (int i = 0; i < 3; ++i) {
        int idx = i * 256 + tid;
        int c = idx / 3, kh = idx % 3;
        float w = Wc[(size_t)o * 768 + idx];
        if (kh == 1) w += Wm[(size_t)o * 512 + 256 + c];
        unsigned short h, l;
        split_bf16(w, h, l);
        wsc[(size_t)(kh * 256 + o) * 256 + c] = h;
        wsc[196608 + (size_t)(kh * 256 + o) * 256 + c] = l;
    }
    float wa = Wm[(size_t)o * 512 + tid];
    unsigned short h, l;
    split_bf16(wa, h, l);
    wsc[393216 + (size_t)o * 256 + tid] = h;
    wsc[458752 + (size_t)o * 256 + tid] = l;
}

// ---- kernel 4a (r20 fused + r21 XCD swizzle): split-bf16 MFMA distances -> top-16 (all rows)
//      + restricted top-24 (keys j < thr) for short-batch blocks.
// r21: grid(1024) flat; b = idx & 7 (fastest) so each XCD's L2 serves ~one batch's key stream.
#define XQH_S 264
#define XKH_S 36
#define DFA_S 66

__global__ __launch_bounds__(256) void k_knn_a(const unsigned int* __restrict__ Xhl,
                                               const double* __restrict__ sq,
                                               const int* __restrict__ nf,
                                               unsigned short* __restrict__ cand,
                                               unsigned short* __restrict__ cand2) {
    __shared__ __align__(16) unsigned short Qh[16 * XQH_S];
    __shared__ __align__(16) unsigned short Ql[16 * XQH_S];
    __shared__ __align__(16) unsigned short Kh[2][64 * XKH_S];
    __shared__ __align__(16) unsigned short Kl[2][64 * XKH_S];
    __shared__ __align__(16) float Df[16 * DFA_S];
    int b  = blockIdx.x & 7;              // batch fastest -> XCD-local key streams
    int q0 = (blockIdx.x >> 3) * 16;
    int tid = threadIdx.x;
    int lane = tid & 63, wave = tid >> 6;
    const unsigned int* xs = Xhl + (size_t)b * NC * NT;
    const double* sqb = sq + b * NT;
    int n = load_nf(nf, b);
    int thr = n + 20;
    bool need2 = (n <= 819) && (q0 + 15 >= thr);   // block-uniform
    float lv[4], lv2[4];
    int li[4], li2[4];
    #pragma unroll
    for (int rr = 0; rr < 4; ++rr) { lv[rr] = INFINITY; li[rr] = 0; lv2[rr] = INFINITY; li2[rr] = 0; }
    #pragma unroll
    for (int i = 0; i < 16; ++i) {
        int idx = tid + i * 256;
        int c = idx >> 4, q = idx & 15;
        unsigned int v = xs[(size_t)c * NT + q0 + q];
        Qh[q * XQH_S + c] = (unsigned short)v;
        Ql[q * XQH_S + c] = (unsigned short)(v >> 16);
    }
    int quad = lane >> 4, l15 = lane & 15;
    int np = wave;
    int qrow = l15;
    int n0 = np * 16 + l15;
    float sqv[4];
    #pragma unroll
    for (int bb = 0; bb < 4; ++bb) sqv[bb] = (float)sqb[q0 + quad * 4 + bb];
    unsigned int pf[8];
    const int nch = (NT / 64) * 8;
    #pragma unroll
    for (int i = 0; i < 8; ++i) pf[i] = xs[(size_t)(wave * 8 + i) * NT + lane];
    store_hl(&Kh[0][lane * XKH_S + wave * 8], &Kl[0][lane * XKH_S + wave * 8], pf);
    #pragma unroll
    for (int i = 0; i < 8; ++i) pf[i] = xs[(size_t)(32 + wave * 8 + i) * NT + lane];
    __syncthreads();
    int ch = 0;
    for (int k0 = 0; k0 < NT; k0 += 64) {
        f32x4 acc0 = {0.f, 0.f, 0.f, 0.f};
        float sk0 = (float)sqb[k0 + n0];
        #pragma unroll
        for (int cc = 0; cc < 8; ++cc) {
            int cur = ch & 1;
            int cb = cc << 5;
            if (ch + 1 < nch) {
                store_hl(&Kh[cur ^ 1][lane * XKH_S + wave * 8],
                         &Kl[cur ^ 1][lane * XKH_S + wave * 8], pf);
            }
            if (ch + 2 < nch) {
                int n2 = ch + 2;
                int nk0 = (n2 >> 3) << 6, ncb = (n2 & 7) << 5;
                #pragma unroll
                for (int i = 0; i < 8; ++i) pf[i] = xs[(size_t)(ncb + wave * 8 + i) * NT + nk0 + lane];
            }
            short8 ah = *(const short8*)&Qh[qrow * XQH_S + cb + quad * 8];
            short8 al = *(const short8*)&Ql[qrow * XQH_S + cb + quad * 8];
            short8 b0h = ld8(&Kh[cur][n0 * XKH_S + quad * 8]);
            short8 b0l = ld8(&Kl[cur][n0 * XKH_S + quad * 8]);
            acc0 = __builtin_amdgcn_mfma_f32_16x16x32_bf16(al, b0h, acc0, 0, 0, 0);
            acc0 = __builtin_amdgcn_mfma_f32_16x16x32_bf16(ah, b0l, acc0, 0, 0, 0);
            acc0 = __builtin_amdgcn_mfma_f32_16x16x32_bf16(ah, b0h, acc0, 0, 0, 0);
            ++ch;
            if (cc < 7) __syncthreads();
        }
        #pragma unroll
        for (int bb = 0; bb < 4; ++bb) {
            int mr = quad * 4 + bb;
            Df[mr * DFA_S + n0] = sqv[bb] + sk0 - 2.f * acc0[bb];
        }
        __syncthreads();
        bool do2 = need2 && (k0 < thr);
        unsigned long long vmask = do2 ? __ballot((k0 + lane) < thr) : 0ull;
        float dnext = Df[(wave * 4) * DFA_S + lane];
        #pragma unroll
        for (int rr = 0; rr < 4; ++rr) {
            float d = dnext;
            if (rr < 3) dnext = Df[(wave * 4 + rr + 1) * DFA_S + lane];
            {
                float thr16 = __shfl(lv[rr], 15);
                unsigned long long mask = __ballot(d < thr16);
                while (mask) {
                    int bit = __ffsll((unsigned long long)mask) - 1;
                    mask &= mask - 1;
                    float vv = __shfl(d, bit);
                    float cur15 = __shfl(lv[rr], 15);
                    if (!(vv < cur15)) continue;
                    int jj = k0 + bit;
                    unsigned long long le = __ballot((lane < 16) && (lv[rr] <= vv));
                    int pos = __popcll(le);
                    float pv = __shfl_up(lv[rr], 1);
                    int pj = __shfl_up(li[rr], 1);
                    if (lane < 16) {
                        if (lane == pos)      { lv[rr] = vv; li[rr] = jj; }
                        else if (lane > pos)  { lv[rr] = pv; li[rr] = pj; }
                    }
                }
            }
            if (do2) {
                float thr24 = __shfl(lv2[rr], 23);
                unsigned long long mask = __ballot(d < thr24) & vmask;
                while (mask) {
                    int bit = __ffsll((unsigned long long)mask) - 1;
                    mask &= mask - 1;
                    float vv = __shfl(d, bit);
                    float cur23 = __shfl(lv2[rr], 23);
                    if (!(vv < cur23)) continue;
                    int jj = k0 + bit;
                    unsigned long long le = __ballot((lane < 24) && (lv2[rr] <= vv));
                    int pos = __popcll(le);
                    float pv = __shfl_up(lv2[rr], 1);
                    int pj = __shfl_up(li2[rr], 1);
                    if (lane < 24) {
                        if (lane == pos)      { lv2[rr] = vv; li2[rr] = jj; }
                        else if (lane > pos)  { lv2[rr] = pv; li2[rr] = pj; }
                    }
                }
            }
        }
    }
    if (lane < 16) {
        #pragma unroll
        for (int rr = 0; rr < 4; ++rr)
            cand[((size_t)b * NT + q0 + wave * 4 + rr) * 16 + lane] = (unsigned short)li[rr];
    }
    if (need2 && lane < 24) {
        #pragma unroll
        for (int rr = 0; rr < 4; ++rr) {
            unsigned short v = (lv2[rr] == INFINITY) ? 0xFFFFu : (unsigned short)li2[rr];
            cand2[((size_t)b * NT + q0 + wave * 4 + rr) * 24 + lane] = v;
        }
    }
}

// ---- kernel 4a2: exact fp64 re-rank of 16 candidates -> nb[0:10) (r12 proven; r21 swizzle) ----
__global__ __launch_bounds__(256) void k_rr1(const float* __restrict__ xT, const double* __restrict__ sq,
                                             const unsigned short* __restrict__ cand, int* __restrict__ nb) {
    int b = blockIdx.x & 7;
    int wave = threadIdx.x >> 6, lane = threadIdx.x & 63;
    int t = (blockIdx.x >> 3) * 4 + wave;
    const float* qp = &xT[((size_t)b * NT + t) * NC];
    float4 q4 = *(const float4*)&qp[lane * 4];
    const unsigned short* cr = &cand[((size_t)b * NT + t) * 16];
    double sqt = sq[b * NT + t];
    double myd = 0.0; int myc = 0;
    for (int i = 0; i < 16; ++i) {
        int t2 = cr[i];
        float4 k4 = *(const float4*)&xT[((size_t)b * NT + t2) * NC + lane * 4];
        double s = fma((double)q4.w, (double)k4.w,
                   fma((double)q4.z, (double)k4.z,
                   fma((double)q4.y, (double)k4.y, (double)q4.x * (double)k4.x)));
        #pragma unroll
        for (int off = 32; off; off >>= 1) s += __shfl_xor(s, off);
        double d = sqt + sq[b * NT + t2] - 2.0 * s;
        if (lane == i) { myd = d; myc = t2; }
    }
    int rank = 0;
    for (int j = 0; j < 16; ++j) {
        double dj = __shfl(myd, j);
        int cj = __shfl(myc, j);
        if (lane < 16 && j != lane)
            rank += ((dj < myd) || (dj == myd && cj < myc)) ? 1 : 0;
    }
    if (lane < 16 && rank < 10) nb[((size_t)b * NT + t) * 10 + rank] = myc;
}

// ---- kernel 4b2: exact fp64 re-rank of restricted candidates; exclusion of nb[0:5); tail -> nb[5:10) ----
__global__ __launch_bounds__(256) void k_rr2(const float* __restrict__ xT, const double* __restrict__ sq,
                                             const int* __restrict__ nf,
                                             const unsigned short* __restrict__ cand2,
                                             int* __restrict__ nb) {
    int b = blockIdx.x & 7;
    int n = load_nf(nf, b);
    if (n > 819) return;
    int thr = n + 20;
    int wave = threadIdx.x >> 6, lane = threadIdx.x & 63;
    int tb = (blockIdx.x >> 3) * 4;
    int t = tb + wave;
    if (tb + 3 < thr) return;
    bool active = (t >= thr);
    const float* qp = &xT[((size_t)b * NT + t) * NC];
    float4 q4 = *(const float4*)&qp[lane * 4];
    const unsigned short* cr = &cand2[((size_t)b * NT + t) * 24];
    double sqt = sq[b * NT + t];
    double myd = DBL_MAX; int myc = 0x7FFFFFFF;
    for (int i = 0; i < 24; ++i) {
        int c16 = cr[i];
        if (c16 == 0xFFFF) continue;
        int t2 = c16;
        float4 k4 = *(const float4*)&xT[((size_t)b * NT + t2) * NC + lane * 4];
        double s = fma((double)q4.w, (double)k4.w,
                   fma((double)q4.z, (double)k4.z,
                   fma((double)q4.y, (double)k4.y, (double)q4.x * (double)k4.x)));
        #pragma unroll
        for (int off = 32; off; off >>= 1) s += __shfl_xor(s, off);
        double d = sqt + sq[b * NT + t2] - 2.0 * s;
        if (lane == i) { myd = d; myc = t2; }
    }
    if (!active) return;
    int f[5];
    #pragma unroll
    for (int s = 0; s < 5; ++s) f[s] = nb[((size_t)b * NT + t) * 10 + s];
    bool keep = (lane < 24) && (myc != 0x7FFFFFFF);
    #pragma unroll
    for (int s = 0; s < 5; ++s) keep = keep && (myc != f[s]);
    int rank = 0;
    for (int j = 0; j < 24; ++j) {
        double dj = __shfl(myd, j);
        int cj = __shfl(myc, j);
        bool kj = __shfl((int)keep, j);
        if (keep && kj && j != lane)
            rank += ((dj < myd) || (dj == myd && cj < myc)) ? 1 : 0;
    }
    if (keep && rank < 5) nb[((size_t)b * NT + t) * 10 + 5 + rank] = myc;
}

// ---- kernel 2 (MFMA, fused): E = conv1d (3 shifted GEMMs) + biases; A = x^T W1^T (4th tap) ----
#define XT_S 40

__global__ __launch_bounds__(256) void k_conv(const float* __restrict__ x, const unsigned short* __restrict__ wsc,
                                              const float* __restrict__ bc, const float* __restrict__ bm,
                                              float* __restrict__ E, float* __restrict__ A) {
    __shared__ __align__(16) unsigned short XTh[66 * XT_S], XTl[66 * XT_S];
    __shared__ __align__(16) unsigned short Wsh[3 * 64 * XT_S], Wsl[3 * 64 * XT_S];
    __shared__ __align__(16) unsigned short Wah[64 * XT_S], Wal[64 * XT_S];
    int tx = blockIdx.x * 64, oy = blockIdx.y * 64, b = blockIdx.z;
    int tid = threadIdx.x, lane = tid & 63, wave = tid >> 6;
    int quad = lane >> 4, l15 = lane & 15;
    f32x4 accE[4] = {}, accA[4] = {};
    for (int c0 = 0; c0 < 256; c0 += 32) {
        __syncthreads();
        #pragma unroll
        for (int i = 0; i < 8; ++i) {
            int c = wave * 8 + i;
            int t = lane;
            int g = tx - 1 + t;
            float v = (g >= 0 && g < NT) ? x[((size_t)b * NC + c0 + c) * NT + g] : 0.f;
            unsigned short h, l;
            split_bf16(v, h, l);
            XTh[t * XT_S + c] = h;
            XTl[t * XT_S + c] = l;
        }
        if (tid < 64) {
            int c = tid >> 1, t = 64 + (tid & 1);
            int g = tx - 1 + t;
            float v = (g < NT) ? x[((size_t)b * NC + c0 + c) * NT + g] : 0.f;
            unsigned short h, l;
            split_bf16(v, h, l);
            XTh[t * XT_S + c] = h;
            XTl[t * XT_S + c] = l;
        }
        #pragma unroll
        for (int i = 0; i < 3; ++i) {
            int gidx = i * 256 + tid;
            int kh = gidx >> 8;
            int o  = (gidx >> 2) & 63;
            int g4 = gidx & 3;
            uint4 vh = *(const uint4*)&wsc[(size_t)(kh * 256 + oy + o) * 256 + c0 + g4 * 8];
            *(uint4*)&Wsh[(kh * 64 + o) * XT_S + g4 * 8] = vh;
            uint4 vl = *(const uint4*)&wsc[196608 + (size_t)(kh * 256 + oy + o) * 256 + c0 + g4 * 8];
            *(uint4*)&Wsl[(kh * 64 + o) * XT_S + g4 * 8] = vl;
        }
        {
            int o = tid >> 2, g4 = tid & 3;
            uint4 vh = *(const uint4*)&wsc[393216 + (size_t)(oy + o) * 256 + c0 + g4 * 8];
            *(uint4*)&Wah[o * XT_S + g4 * 8] = vh;
            uint4 vl = *(const uint4*)&wsc[458752 + (size_t)(oy + o) * 256 + c0 + g4 * 8];
            *(uint4*)&Wal[o * XT_S + g4 * 8] = vl;
        }
        __syncthreads();
        int trow = wave * 16 + l15;
        short8 a_h[3], a_l[3];
        #pragma unroll
        for (int kh = 0; kh < 3; ++kh) {
            a_h[kh] = *(const short8*)&XTh[(trow + kh) * XT_S + quad * 8];
            a_l[kh] = *(const short8*)&XTl[(trow + kh) * XT_S + quad * 8];
        }
        #pragma unroll
        for (int ns = 0; ns < 4; ++ns) {
            int orow = ns * 16 + l15;
            short8 wa_h = *(const short8*)&Wah[orow * XT_S + quad * 8];
            short8 wa_l = *(const short8*)&Wal[orow * XT_S + quad * 8];
            accA[ns] = __builtin_amdgcn_mfma_f32_16x16x32_bf16(a_l[1], wa_h, accA[ns], 0, 0, 0);
            accA[ns] = __builtin_amdgcn_mfma_f32_16x16x32_bf16(a_h[1], wa_l, accA[ns], 0, 0, 0);
            accA[ns] = __builtin_amdgcn_mfma_f32_16x16x32_bf16(a_h[1], wa_h, accA[ns], 0, 0, 0);
            #pragma unroll
            for (int kh = 0; kh < 3; ++kh) {
                short8 w_h = *(const short8*)&Wsh[(kh * 64 + orow) * XT_S + quad * 8];
                short8 w_l = *(const short8*)&Wsl[(kh * 64 + orow) * XT_S + quad * 8];
                accE[ns] = __builtin_amdgcn_mfma_f32_16x16x32_bf16(a_l[kh], w_h, accE[ns], 0, 0, 0);
                accE[ns] = __builtin_amdgcn_mfma_f32_16x16x32_bf16(a_h[kh], w_l, accE[ns], 0, 0, 0);
                accE[ns] = __builtin_amdgcn_mfma_f32_16x16x32_bf16(a_h[kh], w_h, accE[ns], 0, 0, 0);
            }
        }
    }
    #pragma unroll
    for (int ns = 0; ns < 4; ++ns) {
        int o = oy + ns * 16 + l15;
        float bias = bc[o] + bm[o];
        #pragma unroll
        for (int r = 0; r < 4; ++r) {
            int t = tx + wave * 16 + quad * 4 + r;
            E[((size_t)b * NT + t) * 256 + o] = accE[ns][r] + bias;
            A[((size_t)b * NT + t) * 256 + o] = accA[ns][r];
        }
    }
}

// ---------------- kernel 5: epilogue — float4 gather-max + E add + relu + pair max-pool ----------------
__global__ __launch_bounds__(256) void k_epi(const float* __restrict__ A, const float* __restrict__ E,
                                             const int* __restrict__ nb, float* __restrict__ out) {
    __shared__ float buf[32 * 260];
    int p0 = blockIdx.x * 32;
    int b = blockIdx.y;
    int tid = threadIdx.x;
    int o4 = tid & 63;
    int pg = tid >> 6;
    for (int pp8 = 0; pp8 < 8; ++pp8) {
        int pp = pg * 8 + pp8;
        int p = p0 + pp;
        float vm[4] = {0.f, 0.f, 0.f, 0.f};
        #pragma unroll
        for (int tt = 0; tt < 2; ++tt) {
            int t = p * 2 + tt;
            const int* nrow = &nb[((size_t)b * NT + t) * 10];
            float gm[4] = {-FLT_MAX, -FLT_MAX, -FLT_MAX, -FLT_MAX};
            #pragma unroll
            for (int k = 0; k < 10; ++k) {
                int t2 = nrow[k] & (NT - 1);
                float4 a = *(const float4*)&A[((size_t)b * NT + t2) * 256 + o4 * 4];
                gm[0] = fmaxf(gm[0], a.x); gm[1] = fmaxf(gm[1], a.y);
                gm[2] = fmaxf(gm[2], a.z); gm[3] = fmaxf(gm[3], a.w);
            }
            float4 e = *(const float4*)&E[((size_t)b * NT + t) * 256 + o4 * 4];
            vm[0] = fmaxf(vm[0], fmaxf(e.x + gm[0], 0.f));
            vm[1] = fmaxf(vm[1], fmaxf(e.y + gm[1], 0.f));
            vm[2] = fmaxf(vm[2], fmaxf(e.z + gm[2], 0.f));
            vm[3] = fmaxf(vm[3], fmaxf(e.w + gm[3], 0.f));
        }
        float4 v = {vm[0], vm[1], vm[2], vm[3]};
        *(float4*)&buf[pp * 260 + o4 * 4] = v;
    }
    __syncthreads();
    #pragma unroll
    for (int i = 0; i < 32; ++i) {
        int idx = tid + i * 256;
        int oo = idx >> 5, pp = idx & 31;
        out[((size_t)b * 256 + oo) * 1024 + p0 + pp] = buf[pp * 260 + oo];
    }
}

extern "C" void kernel_launch(void* const* d_in, const int* in_sizes, int n_in,
                              void* d_out, int out_size, void* d_ws, size_t ws_size,
                              hipStream_t stream) {
    const float* x  = (const float*)d_in[0];
    const int*   nf = (const int*)d_in[1];
    const float* Wc = (const float*)d_in[2];
    const float* bc = (const float*)d_in[3];
    const float* Wm = (const float*)d_in[4];
    const float* bm = (const float*)d_in[5];
    float* out = (float*)d_out;
    char* ws = (char*)d_ws;
    double* sq = (double*)(ws + SQ_OFF);
    float* A   = (float*)(ws + A_OFF);
    float* E   = (float*)(ws + E_OFF);
    int* nb    = (int*)(ws + NB_OFF);
    unsigned int* Xhl = (unsigned int*)(ws + A_OFF);              // phase A (dead before k_conv)
    float* xT = (float*)(ws + E_OFF);                             // phase A (dead before k_conv)
    unsigned short* wsc   = (unsigned short*)d_out;               // d_out scratch (dead before k_epi)
    unsigned short* cand  = (unsigned short*)d_out + (1 << 20);
    unsigned short* cand2 = (unsigned short*)d_out + (1 << 20) + (1 << 19);

    k_sq<<<dim3(64, 8), dim3(256), 0, stream>>>(x, sq, Xhl);
    k_xt<<<dim3(32, 4, 8), dim3(256), 0, stream>>>(x, xT);
    k_wsplit<<<dim3(256), dim3(256), 0, stream>>>(Wc, Wm, wsc);
    k_knn_a<<<dim3(1024), dim3(256), 0, stream>>>(Xhl, sq, nf, cand, cand2);
    k_rr1<<<dim3(4096), dim3(256), 0, stream>>>(xT, sq, cand, nb);
    k_rr2<<<dim3(4096), dim3(256), 0, stream>>>(xT, sq, nf, cand2, nb);
    k_conv<<<dim3(32, 4, 8), dim3(256), 0, stream>>>(x, wsc, bc, bm, E, A);
    k_epi<<<dim3(32, 8), dim3(256), 0, stream>>>(A, E, nb, out);
}

// Round 22
// 627.587 us; speedup vs baseline: 1.0466x; 1.0466x over previous
//
#include <hip/hip_runtime.h>
#include <hip/hip_bf16.h>
#include <math.h>
#include <float.h>

#define NC 256
#define NT 2048

typedef __attribute__((ext_vector_type(4))) float f32x4;
typedef __attribute__((ext_vector_type(8))) short short8;
typedef __attribute__((ext_vector_type(4))) short short4v;
typedef __attribute__((ext_vector_type(4))) unsigned short ushort4v;

// ws layout (34,340,864 B total — known-good size):
//   sq   double[8*2048]        @ 0
//   A-region @ A_OFF: phase A = Xhl u32[8][256][2048]; phase B = A float
//   E-region @ E_OFF: phase A = xT float[8*2048*256]; phase B = E float
//   nb   int[8*2048*10]        @ NB_OFF
// d_out scratch until k_epi: wsc u16 @ 0; cand u16 @ u16-elem 1<<20; cand2 u16 @ (1<<20)+(1<<19)
#define SQ_OFF 0
#define A_OFF  131072
#define E_OFF  16908288
#define NB_OFF 33685504

__device__ __forceinline__ int load_nf(const int* __restrict__ nf, int b) {
    bool is64 = (nf[1] == 0) & (nf[3] == 0) & (nf[5] == 0) & (nf[7] == 0);
    return is64 ? nf[2 * b] : nf[b];
}

__device__ __forceinline__ void split_bf16(float f, unsigned short& h, unsigned short& l) {
    __hip_bfloat16 hb = __float2bfloat16(f);
    float fh = __bfloat162float(hb);
    __hip_bfloat16 lb = __float2bfloat16(f - fh);
    h = *(unsigned short*)&hb;
    l = *(unsigned short*)&lb;
}

__device__ __forceinline__ short8 ld8(const unsigned short* p) {
    short4v a = *(const short4v*)p;
    short4v b = *(const short4v*)(p + 4);
    return __builtin_shufflevector(a, b, 0, 1, 2, 3, 4, 5, 6, 7);
}

__device__ __forceinline__ void store_hl(unsigned short* dh, unsigned short* dl,
                                         const unsigned int* pf) {
    ushort4v h0 = {(unsigned short)pf[0], (unsigned short)pf[1],
                   (unsigned short)pf[2], (unsigned short)pf[3]};
    ushort4v h1 = {(unsigned short)pf[4], (unsigned short)pf[5],
                   (unsigned short)pf[6], (unsigned short)pf[7]};
    ushort4v l0 = {(unsigned short)(pf[0] >> 16), (unsigned short)(pf[1] >> 16),
                   (unsigned short)(pf[2] >> 16), (unsigned short)(pf[3] >> 16)};
    ushort4v l1 = {(unsigned short)(pf[4] >> 16), (unsigned short)(pf[5] >> 16),
                   (unsigned short)(pf[6] >> 16), (unsigned short)(pf[7] >> 16)};
    *(ushort4v*)dh = h0;
    *(ushort4v*)(dh + 4) = h1;
    *(ushort4v*)dl = l0;
    *(ushort4v*)(dl + 4) = l1;
}

// ---------------- kernel 1: sq + packed bf16-split plane Xhl ----------------
__global__ __launch_bounds__(256) void k_sq(const float* __restrict__ x, double* __restrict__ sq,
                                            unsigned int* __restrict__ Xhl) {
    __shared__ double part[8][33];
    int b = blockIdx.y;
    int q0 = blockIdx.x * 32;
    int tid = threadIdx.x;
    int tt = tid & 31, cg = tid >> 5;
    const float* xp = x + (size_t)b * NC * NT + q0 + tt;
    unsigned int* xo = Xhl + (size_t)b * NC * NT + q0 + tt;
    double a = 0.0;
    #pragma unroll 8
    for (int i = 0; i < 32; ++i) {
        float f = xp[(size_t)(cg * 32 + i) * NT];
        double v = (double)f;
        a = fma(v, v, a);
        unsigned short h, l;
        split_bf16(f, h, l);
        xo[(size_t)(cg * 32 + i) * NT] = (unsigned int)h | ((unsigned int)l << 16);
    }
    part[cg][tt] = a;
    __syncthreads();
    if (tid < 32) {
        double s = part[0][tid];
        #pragma unroll
        for (int g = 1; g < 8; ++g) s += part[g][tid];
        sq[b * NT + q0 + tid] = s;
    }
}

// ---------------- kernel 1b: xT[b][t][c] = x[b][c][t] ----------------
__global__ __launch_bounds__(256) void k_xt(const float* __restrict__ x, float* __restrict__ xT) {
    __shared__ float T[64][65];
    int t0 = blockIdx.x * 64, c0 = blockIdx.y * 64, b = blockIdx.z;
    int tid = threadIdx.x;
    int j = tid & 63, i0 = tid >> 6;
    #pragma unroll
    for (int i = 0; i < 16; ++i) {
        int c = i * 4 + i0;
        T[c][j] = x[((size_t)b * NC + c0 + c) * NT + t0 + j];
    }
    __syncthreads();
    #pragma unroll
    for (int i = 0; i < 16; ++i) {
        int t = i * 4 + i0;
        xT[((size_t)b * NT + t0 + t) * NC + c0 + j] = T[j][t];
    }
}

// ---------------- kernel 1c: pre-split weights into d_out scratch ----------------
__global__ __launch_bounds__(256) void k_wsplit(const float* __restrict__ Wc, const float* __restrict__ Wm,
                                                unsigned short* __restrict__ wsc) {
    int o = blockIdx.x;
    int tid = threadIdx.x;
    #pragma unroll
    for (int i = 0; i < 3; ++i) {
        int idx = i * 256 + tid;
        int c = idx / 3, kh = idx % 3;
        float w = Wc[(size_t)o * 768 + idx];
        if (kh == 1) w += Wm[(size_t)o * 512 + 256 + c];
        unsigned short h, l;
        split_bf16(w, h, l);
        wsc[(size_t)(kh * 256 + o) * 256 + c] = h;
        wsc[196608 + (size_t)(kh * 256 + o) * 256 + c] = l;
    }
    float wa = Wm[(size_t)o * 512 + tid];
    unsigned short h, l;
    split_bf16(wa, h, l);
    wsc[393216 + (size_t)o * 256 + tid] = h;
    wsc[458752 + (size_t)o * 256 + tid] = l;
}

// ---- kernel 4a (r20 best-known): split-bf16 MFMA distances -> top-16 (all rows) + fused
//      restricted top-24 (keys j < thr) for short-batch blocks.
#define XQH_S 264
#define XKH_S 36
#define DFA_S 66

__global__ __launch_bounds__(256) void k_knn_a(const unsigned int* __restrict__ Xhl,
                                               const double* __restrict__ sq,
                                               const int* __restrict__ nf,
                                               unsigned short* __restrict__ cand,
                                               unsigned short* __restrict__ cand2) {
    __shared__ __align__(16) unsigned short Qh[16 * XQH_S];
    __shared__ __align__(16) unsigned short Ql[16 * XQH_S];
    __shared__ __align__(16) unsigned short Kh[2][64 * XKH_S];
    __shared__ __align__(16) unsigned short Kl[2][64 * XKH_S];
    __shared__ __align__(16) float Df[16 * DFA_S];
    int q0 = blockIdx.x * 16;
    int b = blockIdx.y;
    int tid = threadIdx.x;
    int lane = tid & 63, wave = tid >> 6;
    const unsigned int* xs = Xhl + (size_t)b * NC * NT;
    const double* sqb = sq + b * NT;
    int n = load_nf(nf, b);
    int thr = n + 20;
    bool need2 = (n <= 819) && (q0 + 15 >= thr);   // block-uniform
    float lv[4], lv2[4];
    int li[4], li2[4];
    #pragma unroll
    for (int rr = 0; rr < 4; ++rr) { lv[rr] = INFINITY; li[rr] = 0; lv2[rr] = INFINITY; li2[rr] = 0; }
    #pragma unroll
    for (int i = 0; i < 16; ++i) {
        int idx = tid + i * 256;
        int c = idx >> 4, q = idx & 15;
        unsigned int v = xs[(size_t)c * NT + q0 + q];
        Qh[q * XQH_S + c] = (unsigned short)v;
        Ql[q * XQH_S + c] = (unsigned short)(v >> 16);
    }
    int quad = lane >> 4, l15 = lane & 15;
    int np = wave;
    int qrow = l15;
    int n0 = np * 16 + l15;
    float sqv[4];
    #pragma unroll
    for (int bb = 0; bb < 4; ++bb) sqv[bb] = (float)sqb[q0 + quad * 4 + bb];
    unsigned int pf[8];
    const int nch = (NT / 64) * 8;
    #pragma unroll
    for (int i = 0; i < 8; ++i) pf[i] = xs[(size_t)(wave * 8 + i) * NT + lane];
    store_hl(&Kh[0][lane * XKH_S + wave * 8], &Kl[0][lane * XKH_S + wave * 8], pf);
    #pragma unroll
    for (int i = 0; i < 8; ++i) pf[i] = xs[(size_t)(32 + wave * 8 + i) * NT + lane];
    __syncthreads();
    int ch = 0;
    for (int k0 = 0; k0 < NT; k0 += 64) {
        f32x4 acc0 = {0.f, 0.f, 0.f, 0.f};
        float sk0 = (float)sqb[k0 + n0];
        #pragma unroll
        for (int cc = 0; cc < 8; ++cc) {
            int cur = ch & 1;
            int cb = cc << 5;
            if (ch + 1 < nch) {
                store_hl(&Kh[cur ^ 1][lane * XKH_S + wave * 8],
                         &Kl[cur ^ 1][lane * XKH_S + wave * 8], pf);
            }
            if (ch + 2 < nch) {
                int n2 = ch + 2;
                int nk0 = (n2 >> 3) << 6, ncb = (n2 & 7) << 5;
                #pragma unroll
                for (int i = 0; i < 8; ++i) pf[i] = xs[(size_t)(ncb + wave * 8 + i) * NT + nk0 + lane];
            }
            short8 ah = *(const short8*)&Qh[qrow * XQH_S + cb + quad * 8];
            short8 al = *(const short8*)&Ql[qrow * XQH_S + cb + quad * 8];
            short8 b0h = ld8(&Kh[cur][n0 * XKH_S + quad * 8]);
            short8 b0l = ld8(&Kl[cur][n0 * XKH_S + quad * 8]);
            acc0 = __builtin_amdgcn_mfma_f32_16x16x32_bf16(al, b0h, acc0, 0, 0, 0);
            acc0 = __builtin_amdgcn_mfma_f32_16x16x32_bf16(ah, b0l, acc0, 0, 0, 0);
            acc0 = __builtin_amdgcn_mfma_f32_16x16x32_bf16(ah, b0h, acc0, 0, 0, 0);
            ++ch;
            if (cc < 7) __syncthreads();
        }
        #pragma unroll
        for (int bb = 0; bb < 4; ++bb) {
            int mr = quad * 4 + bb;
            Df[mr * DFA_S + n0] = sqv[bb] + sk0 - 2.f * acc0[bb];
        }
        __syncthreads();
        bool do2 = need2 && (k0 < thr);                               // wave-uniform
        unsigned long long vmask = do2 ? __ballot((k0 + lane) < thr) : 0ull;
        float dnext = Df[(wave * 4) * DFA_S + lane];
        #pragma unroll
        for (int rr = 0; rr < 4; ++rr) {
            float d = dnext;
            if (rr < 3) dnext = Df[(wave * 4 + rr + 1) * DFA_S + lane];
            // list 1: unrestricted top-16
            {
                float thr16 = __shfl(lv[rr], 15);
                unsigned long long mask = __ballot(d < thr16);
                while (mask) {
                    int bit = __ffsll((unsigned long long)mask) - 1;
                    mask &= mask - 1;
                    float vv = __shfl(d, bit);
                    float cur15 = __shfl(lv[rr], 15);
                    if (!(vv < cur15)) continue;
                    int jj = k0 + bit;
                    unsigned long long le = __ballot((lane < 16) && (lv[rr] <= vv));
                    int pos = __popcll(le);
                    float pv = __shfl_up(lv[rr], 1);
                    int pj = __shfl_up(li[rr], 1);
                    if (lane < 16) {
                        if (lane == pos)      { lv[rr] = vv; li[rr] = jj; }
                        else if (lane > pos)  { lv[rr] = pv; li[rr] = pj; }
                    }
                }
            }
            // list 2: restricted top-24 (keys j < thr), short-batch blocks only
            if (do2) {
                float thr24 = __shfl(lv2[rr], 23);
                unsigned long long mask = __ballot(d < thr24) & vmask;
                while (mask) {
                    int bit = __ffsll((unsigned long long)mask) - 1;
                    mask &= mask - 1;
                    float vv = __shfl(d, bit);
                    float cur23 = __shfl(lv2[rr], 23);
                    if (!(vv < cur23)) continue;
                    int jj = k0 + bit;
                    unsigned long long le = __ballot((lane < 24) && (lv2[rr] <= vv));
                    int pos = __popcll(le);
                    float pv = __shfl_up(lv2[rr], 1);
                    int pj = __shfl_up(li2[rr], 1);
                    if (lane < 24) {
                        if (lane == pos)      { lv2[rr] = vv; li2[rr] = jj; }
                        else if (lane > pos)  { lv2[rr] = pv; li2[rr] = pj; }
                    }
                }
            }
        }
    }
    if (lane < 16) {
        #pragma unroll
        for (int rr = 0; rr < 4; ++rr)
            cand[((size_t)b * NT + q0 + wave * 4 + rr) * 16 + lane] = (unsigned short)li[rr];
    }
    if (need2 && lane < 24) {
        #pragma unroll
        for (int rr = 0; rr < 4; ++rr) {
            unsigned short v = (lv2[rr] == INFINITY) ? 0xFFFFu : (unsigned short)li2[rr];
            cand2[((size_t)b * NT + q0 + wave * 4 + rr) * 24 + lane] = v;
        }
    }
}

// ---- kernel 4a2: exact fp64 re-rank of 16 candidates -> nb[0:10) (r12 proven) ----
__global__ __launch_bounds__(256) void k_rr1(const float* __restrict__ xT, const double* __restrict__ sq,
                                             const unsigned short* __restrict__ cand, int* __restrict__ nb) {
    int b = blockIdx.y;
    int wave = threadIdx.x >> 6, lane = threadIdx.x & 63;
    int t = blockIdx.x * 4 + wave;
    const float* qp = &xT[((size_t)b * NT + t) * NC];
    float4 q4 = *(const float4*)&qp[lane * 4];
    const unsigned short* cr = &cand[((size_t)b * NT + t) * 16];
    double sqt = sq[b * NT + t];
    double myd = 0.0; int myc = 0;
    for (int i = 0; i < 16; ++i) {
        int t2 = cr[i];
        float4 k4 = *(const float4*)&xT[((size_t)b * NT + t2) * NC + lane * 4];
        double s = fma((double)q4.w, (double)k4.w,
                   fma((double)q4.z, (double)k4.z,
                   fma((double)q4.y, (double)k4.y, (double)q4.x * (double)k4.x)));
        #pragma unroll
        for (int off = 32; off; off >>= 1) s += __shfl_xor(s, off);
        double d = sqt + sq[b * NT + t2] - 2.0 * s;
        if (lane == i) { myd = d; myc = t2; }
    }
    int rank = 0;
    for (int j = 0; j < 16; ++j) {
        double dj = __shfl(myd, j);
        int cj = __shfl(myc, j);
        if (lane < 16 && j != lane)
            rank += ((dj < myd) || (dj == myd && cj < myc)) ? 1 : 0;
    }
    if (lane < 16 && rank < 10) nb[((size_t)b * NT + t) * 10 + rank] = myc;
}

// ---- kernel 4b2: exact fp64 re-rank of restricted candidates; exclusion of nb[0:5); tail -> nb[5:10) ----
__global__ __launch_bounds__(256) void k_rr2(const float* __restrict__ xT, const double* __restrict__ sq,
                                             const int* __restrict__ nf,
                                             const unsigned short* __restrict__ cand2,
                                             int* __restrict__ nb) {
    int b = blockIdx.y;
    int n = load_nf(nf, b);
    if (n > 819) return;
    int thr = n + 20;
    int wave = threadIdx.x >> 6, lane = threadIdx.x & 63;
    int t = blockIdx.x * 4 + wave;
    if (blockIdx.x * 4 + 3 < thr) return;
    bool active = (t >= thr);
    const float* qp = &xT[((size_t)b * NT + t) * NC];
    float4 q4 = *(const float4*)&qp[lane * 4];
    const unsigned short* cr = &cand2[((size_t)b * NT + t) * 24];
    double sqt = sq[b * NT + t];
    double myd = DBL_MAX; int myc = 0x7FFFFFFF;
    for (int i = 0; i < 24; ++i) {
        int c16 = cr[i];
        if (c16 == 0xFFFF) continue;
        int t2 = c16;
        float4 k4 = *(const float4*)&xT[((size_t)b * NT + t2) * NC + lane * 4];
        double s = fma((double)q4.w, (double)k4.w,
                   fma((double)q4.z, (double)k4.z,
                   fma((double)q4.y, (double)k4.y, (double)q4.x * (double)k4.x)));
        #pragma unroll
        for (int off = 32; off; off >>= 1) s += __shfl_xor(s, off);
        double d = sqt + sq[b * NT + t2] - 2.0 * s;
        if (lane == i) { myd = d; myc = t2; }
    }
    if (!active) return;
    int f[5];
    #pragma unroll
    for (int s = 0; s < 5; ++s) f[s] = nb[((size_t)b * NT + t) * 10 + s];
    bool keep = (lane < 24) && (myc != 0x7FFFFFFF);
    #pragma unroll
    for (int s = 0; s < 5; ++s) keep = keep && (myc != f[s]);
    int rank = 0;
    for (int j = 0; j < 24; ++j) {
        double dj = __shfl(myd, j);
        int cj = __shfl(myc, j);
        bool kj = __shfl((int)keep, j);
        if (keep && kj && j != lane)
            rank += ((dj < myd) || (dj == myd && cj < myc)) ? 1 : 0;
    }
    if (keep && rank < 5) nb[((size_t)b * NT + t) * 10 + 5 + rank] = myc;
}

// ---- kernel 2 (MFMA, fused): E = conv1d (3 shifted GEMMs) + biases; A = x^T W1^T (4th tap) ----
#define XT_S 40

__global__ __launch_bounds__(256) void k_conv(const float* __restrict__ x, const unsigned short* __restrict__ wsc,
                                              const float* __restrict__ bc, const float* __restrict__ bm,
                                              float* __restrict__ E, float* __restrict__ A) {
    __shared__ __align__(16) unsigned short XTh[66 * XT_S], XTl[66 * XT_S];
    __shared__ __align__(16) unsigned short Wsh[3 * 64 * XT_S], Wsl[3 * 64 * XT_S];
    __shared__ __align__(16) unsigned short Wah[64 * XT_S], Wal[64 * XT_S];
    int tx = blockIdx.x * 64, oy = blockIdx.y * 64, b = blockIdx.z;
    int tid = threadIdx.x, lane = tid & 63, wave = tid >> 6;
    int quad = lane >> 4, l15 = lane & 15;
    f32x4 accE[4] = {}, accA[4] = {};
    for (int c0 = 0; c0 < 256; c0 += 32) {
        __syncthreads();
        #pragma unroll
        for (int i = 0; i < 8; ++i) {
            int c = wave * 8 + i;
            int t = lane;
            int g = tx - 1 + t;
            float v = (g >= 0 && g < NT) ? x[((size_t)b * NC + c0 + c) * NT + g] : 0.f;
            unsigned short h, l;
            split_bf16(v, h, l);
            XTh[t * XT_S + c] = h;
            XTl[t * XT_S + c] = l;
        }
        if (tid < 64) {
            int c = tid >> 1, t = 64 + (tid & 1);
            int g = tx - 1 + t;
            float v = (g < NT) ? x[((size_t)b * NC + c0 + c) * NT + g] : 0.f;
            unsigned short h, l;
            split_bf16(v, h, l);
            XTh[t * XT_S + c] = h;
            XTl[t * XT_S + c] = l;
        }
        #pragma unroll
        for (int i = 0; i < 3; ++i) {
            int gidx = i * 256 + tid;
            int kh = gidx >> 8;
            int o  = (gidx >> 2) & 63;
            int g4 = gidx & 3;
            uint4 vh = *(const uint4*)&wsc[(size_t)(kh * 256 + oy + o) * 256 + c0 + g4 * 8];
            *(uint4*)&Wsh[(kh * 64 + o) * XT_S + g4 * 8] = vh;
            uint4 vl = *(const uint4*)&wsc[196608 + (size_t)(kh * 256 + oy + o) * 256 + c0 + g4 * 8];
            *(uint4*)&Wsl[(kh * 64 + o) * XT_S + g4 * 8] = vl;
        }
        {
            int o = tid >> 2, g4 = tid & 3;
            uint4 vh = *(const uint4*)&wsc[393216 + (size_t)(oy + o) * 256 + c0 + g4 * 8];
            *(uint4*)&Wah[o * XT_S + g4 * 8] = vh;
            uint4 vl = *(const uint4*)&wsc[458752 + (size_t)(oy + o) * 256 + c0 + g4 * 8];
            *(uint4*)&Wal[o * XT_S + g4 * 8] = vl;
        }
        __syncthreads();
        int trow = wave * 16 + l15;
        short8 a_h[3], a_l[3];
        #pragma unroll
        for (int kh = 0; kh < 3; ++kh) {
            a_h[kh] = *(const short8*)&XTh[(trow + kh) * XT_S + quad * 8];
            a_l[kh] = *(const short8*)&XTl[(trow + kh) * XT_S + quad * 8];
        }
        #pragma unroll
        for (int ns = 0; ns < 4; ++ns) {
            int orow = ns * 16 + l15;
            short8 wa_h = *(const short8*)&Wah[orow * XT_S + quad * 8];
            short8 wa_l = *(const short8*)&Wal[orow * XT_S + quad * 8];
            accA[ns] = __builtin_amdgcn_mfma_f32_16x16x32_bf16(a_l[1], wa_h, accA[ns], 0, 0, 0);
            accA[ns] = __builtin_amdgcn_mfma_f32_16x16x32_bf16(a_h[1], wa_l, accA[ns], 0, 0, 0);
            accA[ns] = __builtin_amdgcn_mfma_f32_16x16x32_bf16(a_h[1], wa_h, accA[ns], 0, 0, 0);
            #pragma unroll
            for (int kh = 0; kh < 3; ++kh) {
                short8 w_h = *(const short8*)&Wsh[(kh * 64 + orow) * XT_S + quad * 8];
                short8 w_l = *(const short8*)&Wsl[(kh * 64 + orow) * XT_S + quad * 8];
                accE[ns] = __builtin_amdgcn_mfma_f32_16x16x32_bf16(a_l[kh], w_h, accE[ns], 0, 0, 0);
                accE[ns] = __builtin_amdgcn_mfma_f32_16x16x32_bf16(a_h[kh], w_l, accE[ns], 0, 0, 0);
                accE[ns] = __builtin_amdgcn_mfma_f32_16x16x32_bf16(a_h[kh], w_h, accE[ns], 0, 0, 0);
            }
        }
    }
    #pragma unroll
    for (int ns = 0; ns < 4; ++ns) {
        int o = oy + ns * 16 + l15;
        float bias = bc[o] + bm[o];
        #pragma unroll
        for (int r = 0; r < 4; ++r) {
            int t = tx + wave * 16 + quad * 4 + r;
            E[((size_t)b * NT + t) * 256 + o] = accE[ns][r] + bias;
            A[((size_t)b * NT + t) * 256 + o] = accA[ns][r];
        }
    }
}

// ---------------- kernel 5: epilogue — float4 gather-max + E add + relu + pair max-pool ----------------
__global__ __launch_bounds__(256) void k_epi(const float* __restrict__ A, const float* __restrict__ E,
                                             const int* __restrict__ nb, float* __restrict__ out) {
    __shared__ float buf[32 * 260];
    int p0 = blockIdx.x * 32;
    int b = blockIdx.y;
    int tid = threadIdx.x;
    int o4 = tid & 63;
    int pg = tid >> 6;
    for (int pp8 = 0; pp8 < 8; ++pp8) {
        int pp = pg * 8 + pp8;
        int p = p0 + pp;
        float vm[4] = {0.f, 0.f, 0.f, 0.f};
        #pragma unroll
        for (int tt = 0; tt < 2; ++tt) {
            int t = p * 2 + tt;
            const int* nrow = &nb[((size_t)b * NT + t) * 10];
            float gm[4] = {-FLT_MAX, -FLT_MAX, -FLT_MAX, -FLT_MAX};
            #pragma unroll
            for (int k = 0; k < 10; ++k) {
                int t2 = nrow[k] & (NT - 1);
                float4 a = *(const float4*)&A[((size_t)b * NT + t2) * 256 + o4 * 4];
                gm[0] = fmaxf(gm[0], a.x); gm[1] = fmaxf(gm[1], a.y);
                gm[2] = fmaxf(gm[2], a.z); gm[3] = fmaxf(gm[3], a.w);
            }
            float4 e = *(const float4*)&E[((size_t)b * NT + t) * 256 + o4 * 4];
            vm[0] = fmaxf(vm[0], fmaxf(e.x + gm[0], 0.f));
            vm[1] = fmaxf(vm[1], fmaxf(e.y + gm[1], 0.f));
            vm[2] = fmaxf(vm[2], fmaxf(e.z + gm[2], 0.f));
            vm[3] = fmaxf(vm[3], fmaxf(e.w + gm[3], 0.f));
        }
        float4 v = {vm[0], vm[1], vm[2], vm[3]};
        *(float4*)&buf[pp * 260 + o4 * 4] = v;
    }
    __syncthreads();
    #pragma unroll
    for (int i = 0; i < 32; ++i) {
        int idx = tid + i * 256;
        int oo = idx >> 5, pp = idx & 31;
        out[((size_t)b * 256 + oo) * 1024 + p0 + pp] = buf[pp * 260 + oo];
    }
}

extern "C" void kernel_launch(void* const* d_in, const int* in_sizes, int n_in,
                              void* d_out, int out_size, void* d_ws, size_t ws_size,
                              hipStream_t stream) {
    const float* x  = (const float*)d_in[0];
    const int*   nf = (const int*)d_in[1];
    const float* Wc = (const float*)d_in[2];
    const float* bc = (const float*)d_in[3];
    const float* Wm = (const float*)d_in[4];
    const float* bm = (const float*)d_in[5];
    float* out = (float*)d_out;
    char* ws = (char*)d_ws;
    double* sq = (double*)(ws + SQ_OFF);
    float* A   = (float*)(ws + A_OFF);
    float* E   = (float*)(ws + E_OFF);
    int* nb    = (int*)(ws + NB_OFF);
    unsigned int* Xhl = (unsigned int*)(ws + A_OFF);              // phase A (dead before k_conv)
    float* xT = (float*)(ws + E_OFF);                             // phase A (dead before k_conv)
    unsigned short* wsc   = (unsigned short*)d_out;               // d_out scratch (dead before k_epi)
    unsigned short* cand  = (unsigned short*)d_out + (1 << 20);
    unsigned short* cand2 = (unsigned short*)d_out + (1 << 20) + (1 << 19);

    k_sq<<<dim3(64, 8), dim3(256), 0, stream>>>(x, sq, Xhl);
    k_xt<<<dim3(32, 4, 8), dim3(256), 0, stream>>>(x, xT);
    k_wsplit<<<dim3(256), dim3(256), 0, stream>>>(Wc, Wm, wsc);
    k_knn_a<<<dim3(128, 8), dim3(256), 0, stream>>>(Xhl, sq, nf, cand, cand2);
    k_rr1<<<dim3(512, 8), dim3(256), 0, stream>>>(xT, sq, cand, nb);
    k_rr2<<<dim3(512, 8), dim3(256), 0, stream>>>(xT, sq, nf, cand2, nb);
    k_conv<<<dim3(32, 4, 8), dim3(256), 0, stream>>>(x, wsc, bc, bm, E, A);
    k_epi<<<dim3(32, 8), dim3(256), 0, stream>>>(A, E, nb, out);
}